// Round 11
// baseline (462.029 us; speedup 1.0000x reference)
//
#include <hip/hip_runtime.h>
#include <math.h>

// ---------------- problem constants (static graph/problem) ----------------
constexpr int NN   = 10000;          // nodes
constexpr int E0C  = 100000;         // edges without self loops
constexpr int EC   = E0C + NN;       // 110000 with self loops
constexpr int INC  = 512;
constexpr int HIDC = 256;
constexpr int OUTC = 10;
constexpr int H1C  = 4;
constexpr int H2C  = 1;
constexpr int ONC  = 2 * HIDC;       // 512
constexpr int D1C  = H1C * HIDC;     // 1024
constexpr int D2C  = H2C * HIDC;     // 256
constexpr int KC   = 5;
constexpr float LOG2PI_F = 1.8378770664093453f;

using u16 = unsigned short;
typedef __attribute__((ext_vector_type(8))) short bf16x8;
typedef __attribute__((ext_vector_type(4))) float f32x4;

// ---------------- helpers ----------------
__device__ __forceinline__ unsigned f2bf(float f) {
    unsigned u = __float_as_uint(f);
    return (u + 0x7fffu + ((u >> 16) & 1u)) >> 16;   // RNE
}
__device__ __forceinline__ float bflo(unsigned u) { return __uint_as_float(u << 16); }
__device__ __forceinline__ float bfhi(unsigned u) { return __uint_as_float(u & 0xffff0000u); }
__device__ __forceinline__ float bf1(u16 v) { return __uint_as_float(((unsigned)v) << 16); }
__device__ __forceinline__ void edge_sd(int e, const int* __restrict__ ei, int& src, int& dst) {
    if (e < E0C) { src = ei[e]; dst = ei[E0C + e]; }
    else         { src = e - E0C; dst = src; }
}
__device__ __forceinline__ float wmax(float x) {
#pragma unroll
    for (int o = 32; o > 0; o >>= 1) x = fmaxf(x, __shfl_xor(x, o, 64));
    return x;
}
__device__ __forceinline__ float wsum(float x) {
#pragma unroll
    for (int o = 32; o > 0; o >>= 1) x += __shfl_xor(x, o, 64);
    return x;
}
// async global->LDS, 16B per lane; dest is wave-uniform base + lane*16
__device__ __forceinline__ void gl_lds16(const u16* g, u16* l) {
    __builtin_amdgcn_global_load_lds(
        (const __attribute__((address_space(1))) unsigned int*)g,
        (__attribute__((address_space(3))) unsigned int*)l, 16, 0, 0);
}

// ---------------- init: zero all accumulators in one dispatch ----------------
__global__ void init_zero(unsigned* __restrict__ deg, unsigned* __restrict__ cursor,
                          unsigned* __restrict__ si1, unsigned* __restrict__ sj1,
                          unsigned* __restrict__ si2, unsigned* __restrict__ sj2,
                          unsigned* __restrict__ kl) {
    int i = blockIdx.x * blockDim.x + threadIdx.x;
    if (i < NN) { deg[i] = 0u; cursor[i] = 0u; }
    if (i < NN * H1C) { si1[i] = 0u; sj1[i] = 0u; }
    if (i < NN * H2C) { si2[i] = 0u; sj2[i] = 0u; }
    if (i < 2) kl[i] = 0u;
}

// ---------------- bf16 cast ----------------
__global__ void cast_bf16(const float* __restrict__ in, u16* __restrict__ o, int n4) {
    int i = blockIdx.x * blockDim.x + threadIdx.x;
    if (i >= n4) return;
    float4 v = ((const float4*)in)[i];
    uint2 r;
    r.x = f2bf(v.x) | (f2bf(v.y) << 16);
    r.y = f2bf(v.z) | (f2bf(v.w) << 16);
    ((uint2*)o)[i] = r;
}

// both weight transposes in one dispatch: W [K][N] fp32 -> WT [N][K] bf16
__global__ __launch_bounds__(256) void transpose_cast_both(const float* __restrict__ W1,
                                                           u16* __restrict__ WT1,
                                                           const float* __restrict__ W2,
                                                           u16* __restrict__ WT2) {
    __shared__ float tile[32][33];
    int bx = blockIdx.x, by = blockIdx.y;
    const float* W; u16* WT; int K, N, n0, k0;
    if (by < 16) { W = W1; WT = WT1; K = 512;  N = 2048; n0 = bx * 32; k0 = by * 32; }
    else {
        if (bx >= 16) return;
        W = W2; WT = WT2; K = 1024; N = 512;  n0 = bx * 32; k0 = (by - 16) * 32;
    }
    int tx = threadIdx.x, ty = threadIdx.y;   // 32 x 8
    for (int r = ty; r < 32; r += 8) tile[r][tx] = W[(size_t)(k0 + r) * N + n0 + tx];
    __syncthreads();
    for (int r = ty; r < 32; r += 8) WT[(size_t)(n0 + r) * K + k0 + tx] = (u16)f2bf(tile[tx][r]);
}

// ---------------- graph preprocessing ----------------
__global__ void count_deg(const int* __restrict__ ei, int* __restrict__ deg) {
    int e = blockIdx.x * blockDim.x + threadIdx.x;
    if (e >= EC) return;
    int dst = (e < E0C) ? ei[E0C + e] : (e - E0C);
    atomicAdd(&deg[dst], 1);
}

__global__ __launch_bounds__(1024) void scan_kernel(const int* __restrict__ deg,
                                                    int* __restrict__ offs) {
    __shared__ int part[1024];
    const int CH = (NN + 1023) / 1024;   // 10
    int tid = threadIdx.x;
    int base = tid * CH;
    int s = 0;
    for (int i = 0; i < CH; i++) { int idx = base + i; if (idx < NN) s += deg[idx]; }
    part[tid] = s;
    __syncthreads();
    for (int o = 1; o < 1024; o <<= 1) {
        int v = (tid >= o) ? part[tid - o] : 0;
        __syncthreads();
        part[tid] += v;
        __syncthreads();
    }
    int run = (tid == 0) ? 0 : part[tid - 1];
    for (int i = 0; i < CH; i++) {
        int idx = base + i;
        if (idx < NN) {
            offs[idx] = run;
            run += deg[idx];
        }
    }
    if (tid == 1023) offs[NN] = run;
}

__global__ void csr_fill(const int* __restrict__ ei, int* __restrict__ cursor,
                         const int* __restrict__ offs, int* __restrict__ csr_src,
                         int* __restrict__ csr_eid) {
    int e = blockIdx.x * blockDim.x + threadIdx.x;
    if (e >= EC) return;
    int src, dst;
    edge_sd(e, ei, src, dst);
    int pos = offs[dst] + atomicAdd(&cursor[dst], 1);
    csr_src[pos] = src;
    csr_eid[pos] = e;
}

// ---------------- m97-style MFMA GEMM (+ fused attention scores) ----------------
// C[M,N] = A@B, BT is [N][K] bf16. global_load_lds width-16 staging, no pad.
// SCORES: epilogue dots fp32 acc with att columns, shfl-reduces over the 16
// col-lanes, atomicAdds into s_i/s_j (each 128-col block lies in one head).
template <int H, bool SCORES>
__global__ __launch_bounds__(256) void mfma_gemm3(const u16* __restrict__ A,
                                                  const u16* __restrict__ BT,
                                                  u16* __restrict__ C,
                                                  const float* __restrict__ att,
                                                  float* __restrict__ s_i,
                                                  float* __restrict__ s_j,
                                                  int M, int N, int K) {
    constexpr int BM = 128, BN = 128, BK = 32;
    __shared__ __align__(16) u16 As[BM * BK];   // rows of 64B, contiguous
    __shared__ __align__(16) u16 Bs[BN * BK];
    const int tid = threadIdx.x;
    const int lane = tid & 63;
    const int wave = tid >> 6;
    const int wm = (wave & 1) * 64;
    const int wn = (wave >> 1) * 64;
    const int row0 = blockIdx.y * BM;
    const int col0 = blockIdx.x * BN;
    const int fr = lane & 15;
    const int fq = (lane >> 4) * 8;
    const int srow = lane >> 2;          // 0..15
    const int scol = (lane & 3) * 8;     // 0,8,16,24 elems (16B chunks)
    const int aRa = wave * 32 + srow;
    const int aRb = aRa + 16;
    const size_t gA0 = (size_t)min(row0 + aRa, M - 1) * K;
    const size_t gA1 = (size_t)min(row0 + aRb, M - 1) * K;
    const size_t gB0 = (size_t)(col0 + aRa) * K;
    const size_t gB1 = (size_t)(col0 + aRb) * K;
    u16* lA0 = &As[(wave * 32) * BK];
    u16* lA1 = &As[(wave * 32 + 16) * BK];
    u16* lB0 = &Bs[(wave * 32) * BK];
    u16* lB1 = &Bs[(wave * 32 + 16) * BK];
    f32x4 acc[4][4] = {};
    for (int k0 = 0; k0 < K; k0 += BK) {
        gl_lds16(A + gA0 + k0 + scol, lA0);
        gl_lds16(A + gA1 + k0 + scol, lA1);
        gl_lds16(BT + gB0 + k0 + scol, lB0);
        gl_lds16(BT + gB1 + k0 + scol, lB1);
        __syncthreads();
        bf16x8 af[4], bfr[4];
#pragma unroll
        for (int i = 0; i < 4; i++) {
            af[i]  = *(const bf16x8*)&As[(wm + i * 16 + fr) * BK + fq];
            bfr[i] = *(const bf16x8*)&Bs[(wn + i * 16 + fr) * BK + fq];
        }
#pragma unroll
        for (int mi = 0; mi < 4; mi++)
#pragma unroll
            for (int ni = 0; ni < 4; ni++)
                acc[mi][ni] = __builtin_amdgcn_mfma_f32_16x16x32_bf16(af[mi], bfr[ni], acc[mi][ni], 0, 0, 0);
        __syncthreads();
    }
    const int cc = lane & 15;
    const int cr = (lane >> 4) * 4;
#pragma unroll
    for (int mi = 0; mi < 4; mi++)
#pragma unroll
        for (int r = 0; r < 4; r++) {
            int grow = row0 + wm + mi * 16 + cr + r;
            if (grow < M) {
#pragma unroll
                for (int ni = 0; ni < 4; ni++)
                    C[(size_t)grow * N + col0 + wn + ni * 16 + cc] = (u16)f2bf(acc[mi][ni][r]);
            }
        }
    if (SCORES) {
        const int head = col0 / ONC;
        const int cb = col0 - head * ONC + wn + cc;   // col' within head (ni=0)
        float aLv[4], aRv[4];
#pragma unroll
        for (int ni = 0; ni < 4; ni++) {
            aLv[ni] = att[head * 2 * ONC + cb + ni * 16];
            aRv[ni] = att[head * 2 * ONC + ONC + cb + ni * 16];
        }
#pragma unroll
        for (int mi = 0; mi < 4; mi++)
#pragma unroll
            for (int r = 0; r < 4; r++) {
                float pi_ = 0.f, pj_ = 0.f;
#pragma unroll
                for (int ni = 0; ni < 4; ni++) {
                    float v = acc[mi][ni][r];
                    pi_ = fmaf(v, aLv[ni], pi_);
                    pj_ = fmaf(v, aRv[ni], pj_);
                }
#pragma unroll
                for (int o = 1; o < 16; o <<= 1) {
                    pi_ += __shfl_xor(pi_, o, 64);
                    pj_ += __shfl_xor(pj_, o, 64);
                }
                int grow = row0 + wm + mi * 16 + cr + r;
                if (cc == 0 && grow < M) {
                    atomicAdd(&s_i[grow * H + head], pi_);
                    atomicAdd(&s_j[grow * H + head], pj_);
                }
            }
    }
}

// ---------------- fused per-segment attention softmax ----------------
template <int H, int PW>
__global__ __launch_bounds__(256) void attn_fused(const int* __restrict__ offs,
                                                  const int* __restrict__ csr_src,
                                                  const int* __restrict__ csr_eid,
                                                  const float* __restrict__ s_i,
                                                  const float* __restrict__ s_j,
                                                  const float* __restrict__ g,
                                                  float* __restrict__ alpha_csr,
                                                  float* __restrict__ kl_acc,
                                                  float scale) {
    const int tid = threadIdx.x;
    const int wave = tid >> 6, lane = tid & 63;
    const int pair0 = (blockIdx.x * 4 + wave) * PW;
    float kl = 0.f;
#pragma unroll 1
    for (int t = 0; t < PW; t++) {
        int pr = pair0 + t;
        if (pr >= NN * H) break;
        int n = pr / H, h = pr - (pr / H) * H;
        int beg = offs[n], end = offs[n + 1];
        int deg = end - beg;
        float si = s_i[n * H + h];
        float ldeg = __logf((float)deg);
        if (deg <= 64) {
            int pos = beg + lane;
            bool v = lane < deg;
            int src = v ? csr_src[pos] : 0;
            int eid = v ? csr_eid[pos] : 0;
            float a = si + s_j[src * H + h];
            a = (a > 0.f) ? a : 0.2f * a;
            if (!v) a = -3.4e38f;
            float m1 = wmax(a);
            float am = v ? (a - m1) : 0.f;
            float e1 = v ? __expf(am) : 0.f;
            float ss1 = wsum(e1);
            float sd  = wsum(e1 * am);
            float lss1 = __logf(ss1);
            kl += sd / ss1 - lss1 + ldeg;
            float l2 = v ? (am - lss1 + g[eid * H + h]) : -3.4e38f;
            float m2 = wmax(l2);
            float e2 = v ? __expf(l2 - m2) : 0.f;
            float ss2 = wsum(e2);
            if (v) alpha_csr[(size_t)pos * H + h] = e2 / ss2;
        } else {
            float m1 = -3.4e38f;
            for (int p = beg + lane; p < end; p += 64) {
                float a = si + s_j[csr_src[p] * H + h];
                a = (a > 0.f) ? a : 0.2f * a;
                m1 = fmaxf(m1, a);
            }
            m1 = wmax(m1);
            float ss1 = 0.f, sd = 0.f;
            for (int p = beg + lane; p < end; p += 64) {
                float a = si + s_j[csr_src[p] * H + h];
                a = (a > 0.f) ? a : 0.2f * a;
                float e1 = __expf(a - m1);
                ss1 += e1; sd += e1 * (a - m1);
            }
            ss1 = wsum(ss1); sd = wsum(sd);
            float lss1 = __logf(ss1);
            kl += sd / ss1 - lss1 + ldeg;
            float m2 = -3.4e38f;
            for (int p = beg + lane; p < end; p += 64) {
                float a = si + s_j[csr_src[p] * H + h];
                a = (a > 0.f) ? a : 0.2f * a;
                m2 = fmaxf(m2, a - m1 - lss1 + g[csr_eid[p] * H + h]);
            }
            m2 = wmax(m2);
            float ss2 = 0.f;
            for (int p = beg + lane; p < end; p += 64) {
                float a = si + s_j[csr_src[p] * H + h];
                a = (a > 0.f) ? a : 0.2f * a;
                ss2 += __expf(a - m1 - lss1 + g[csr_eid[p] * H + h] - m2);
            }
            ss2 = wsum(ss2);
            for (int p = beg + lane; p < end; p += 64) {
                float a = si + s_j[csr_src[p] * H + h];
                a = (a > 0.f) ? a : 0.2f * a;
                alpha_csr[(size_t)p * H + h] =
                    __expf(a - m1 - lss1 + g[csr_eid[p] * H + h] - m2) / ss2;
            }
        }
    }
    __shared__ float red[4];
    if (lane == 0) red[wave] = kl;
    __syncthreads();
    if (tid == 0)
        atomicAdd(kl_acc, (red[0] + red[1] + red[2] + red[3]) * scale);
}

// ---------------- panel-pinned CSR gather: 2 nodes/wave, 16B/lane, unroll 8 ----------------
template <int H, int NP>
__global__ __launch_bounds__(256) void gather_reg2(const u16* __restrict__ xh,
                                                   const float* __restrict__ alpha_csr,
                                                   const int* __restrict__ offs,
                                                   const int* __restrict__ csr_src,
                                                   u16* __restrict__ out) {
    constexpr int ROW = H * ONC;
    constexpr int CPP = ROW / NP;     // 256 channels per panel
    constexpr int CL  = CPP / 32;     // 8 channels per lane (uint4)
    const int bx = blockIdx.x;
    const int panel = bx % NP;
    const int wave = threadIdx.x >> 6;
    const int lane = threadIdx.x & 63;
    const int half = lane >> 5;              // which node of the pair
    const int l32  = lane & 31;
    const int n = (bx / NP) * 8 + wave * 2 + half;
    const int head = (panel * CPP) / ONC;
    const int c0 = panel * CPP + l32 * CL;
    const int beg = offs[n], end = offs[n + 1];
    const int deg = end - beg;
    const int degO = __shfl_xor(deg, 32, 64);    // partner node's degree
    const int mdeg = max(deg, degO);
    const int bsel = half << 5;
    float acc[CL];
#pragma unroll
    for (int j = 0; j < CL; j++) acc[j] = 0.f;
    for (int c = 0; c < mdeg; c += 32) {
        bool v = (c + l32) < deg;
        int myp = beg + c + l32;
        int   srcv = v ? csr_src[myp] : 0;
        float wv   = v ? alpha_csr[(size_t)myp * H + head] : 0.f;
        int cnt = min(32, mdeg - c);
#pragma unroll 8
        for (int t = 0; t < cnt; t++) {
            int   s = __shfl(srcv, bsel + t, 64);
            float w = __shfl(wv,   bsel + t, 64);
            const u16* xr = xh + (size_t)s * ROW + c0;
            uint4 val = *(const uint4*)xr;
            acc[0] = fmaf(w, bflo(val.x), acc[0]);
            acc[1] = fmaf(w, bfhi(val.x), acc[1]);
            acc[2] = fmaf(w, bflo(val.y), acc[2]);
            acc[3] = fmaf(w, bfhi(val.y), acc[3]);
            acc[4] = fmaf(w, bflo(val.z), acc[4]);
            acc[5] = fmaf(w, bfhi(val.z), acc[5]);
            acc[6] = fmaf(w, bflo(val.w), acc[6]);
            acc[7] = fmaf(w, bfhi(val.w), acc[7]);
        }
    }
    u16* orow = out + (size_t)n * ROW + c0;
    uint4 r;
    r.x = f2bf(acc[0]) | (f2bf(acc[1]) << 16);
    r.y = f2bf(acc[2]) | (f2bf(acc[3]) << 16);
    r.z = f2bf(acc[4]) | (f2bf(acc[5]) << 16);
    r.w = f2bf(acc[6]) | (f2bf(acc[7]) << 16);
    *(uint4*)orow = r;
}

// ---------------- mixture-prior quadratic tables (both layers, one dispatch) ----------------
__device__ __forceinline__ void mix_one(const float* __restrict__ pi, const float* __restrict__ mu,
                                        const float* __restrict__ logsig, float* __restrict__ tab,
                                        int DK, int i) {
    int k = i % KC;
    float p[KC]; float mx = -3.4e38f;
#pragma unroll
    for (int j = 0; j < KC; j++) { p[j] = pi[j]; mx = fmaxf(mx, p[j]); }
    float s = 0.f;
#pragma unroll
    for (int j = 0; j < KC; j++) s += expf(p[j] - mx);
    float lpi = p[k] - (mx + logf(s));
    float ls = logsig[i];
    float inv = expf(-ls);
    float inv2 = inv * inv;
    float m = mu[i];
    tab[i]          = -0.5f * inv2;                                      // a
    tab[DK + i]     = inv2 * m;                                          // b
    tab[2 * DK + i] = -0.5f * inv2 * m * m - ls - 0.5f * LOG2PI_F + lpi; // c
}

__global__ void mix_tables(const float* __restrict__ pi1, const float* __restrict__ mu1,
                           const float* __restrict__ ls1, float* __restrict__ tab1,
                           const float* __restrict__ pi2, const float* __restrict__ mu2,
                           const float* __restrict__ ls2, float* __restrict__ tab2) {
    int i = blockIdx.x * blockDim.x + threadIdx.x;
    if (i < D1C * KC) mix_one(pi1, mu1, ls1, tab1, D1C * KC, i);
    else {
        int j = i - D1C * KC;
        if (j < D2C * KC) mix_one(pi2, mu2, ls2, tab2, D2C * KC, j);
    }
}

// ---------------- zixz v4: thread owns 4 channels, block covers full D (H=4) ----------------
template <int NT, bool BF16OUT>
__global__ __launch_bounds__(256) void zixz4_kernel(const u16* __restrict__ in_agg,
                                                    const float* __restrict__ eps,
                                                    const float* __restrict__ tab,
                                                    void* __restrict__ hout_,
                                                    float* __restrict__ ixz_acc) {
    constexpr int H = H1C;
    constexpr int D = H * HIDC;       // 1024
    constexpr int DK = D * KC;
    const int tid = threadIdx.x;
    const int d0 = tid * 4;
    const int head = d0 >> 8;
    const int c = d0 & 255;
    const int moff = head * ONC + c;
    float ca[4][KC], cb[4][KC], cv[4][KC];
#pragma unroll
    for (int j = 0; j < 4; j++)
#pragma unroll
        for (int k = 0; k < KC; k++) {
            ca[j][k] = tab[(d0 + j) * KC + k];
            cb[j][k] = tab[DK + (d0 + j) * KC + k];
            cv[j][k] = tab[2 * DK + (d0 + j) * KC + k];
        }
    const int n0 = blockIdx.x * NT;
    float local = 0.f;
#pragma unroll 1
    for (int nn = 0; nn < NT; nn++) {
        int n = n0 + nn;
        const u16* orow = in_agg + (size_t)n * (H * ONC);
        uint2 vm = *(const uint2*)(orow + moff);
        uint2 vr = *(const uint2*)(orow + moff + HIDC);
        float4 ep4 = *(const float4*)(eps + (size_t)n * D + d0);
        float mean[4] = { bflo(vm.x), bfhi(vm.x), bflo(vm.y), bfhi(vm.y) };
        float raw[4]  = { bflo(vr.x), bfhi(vr.x), bflo(vr.y), bfhi(vr.y) };
        float epq[4]  = { ep4.x, ep4.y, ep4.z, ep4.w };
        float hv4[4];
#pragma unroll
        for (int j = 0; j < 4; j++) {
            float sp = fmaxf(raw[j], 0.f) + __logf(1.f + __expf(-fabsf(raw[j])));
            float stdv = sp + 1e-10f;
            float ep = epq[j];
            float Z = fmaf(stdv, ep, mean[j]);
            hv4[j] = (Z > 0.f) ? Z : (__expf(Z) - 1.f);
            float logq = fmaf(-0.5f, ep * ep, -__logf(stdv)) - 0.5f * LOG2PI_F;
            float comp[KC]; float mx = -3.4e38f;
#pragma unroll
            for (int k = 0; k < KC; k++) {
                float cval = fmaf(fmaf(ca[j][k], Z, cb[j][k]), Z, cv[j][k]);
                comp[k] = cval;
                mx = fmaxf(mx, cval);
            }
            float se = 0.f;
#pragma unroll
            for (int k = 0; k < KC; k++) se += __expf(comp[k] - mx);
            local += logq - (mx + __logf(se));
        }
        if (BF16OUT) {
            uint2 r;
            r.x = f2bf(hv4[0]) | (f2bf(hv4[1]) << 16);
            r.y = f2bf(hv4[2]) | (f2bf(hv4[3]) << 16);
            *(uint2*)((u16*)hout_ + (size_t)n * D + d0) = r;
        } else {
            *(float4*)((float*)hout_ + (size_t)n * D + d0) =
                make_float4(hv4[0], hv4[1], hv4[2], hv4[3]);
        }
    }
#pragma unroll
    for (int o = 32; o > 0; o >>= 1) local += __shfl_down(local, o, 64);
    __shared__ float red[4];
    int lane = tid & 63, wid = tid >> 6;
    if (lane == 0) red[wid] = local;
    __syncthreads();
    if (tid == 0)
        atomicAdd(ixz_acc, (red[0] + red[1] + red[2] + red[3]) * (1.0f / NN));
}

// ---------------- zixz v3 (thread-owns-channel) — layer 2 (H=1) ----------------
template <int H, int NT, bool BF16OUT>
__global__ __launch_bounds__(256) void zixz3_kernel(const u16* __restrict__ in_agg,
                                                    const float* __restrict__ eps,
                                                    const float* __restrict__ tab,
                                                    void* __restrict__ hout_,
                                                    float* __restrict__ ixz_acc) {
    constexpr int D = H * HIDC;
    constexpr int DK = D * KC;
    const int tid = threadIdx.x;
    const int h = blockIdx.y;
    const int d = h * HIDC + tid;
    float ca[KC], cb[KC], cc[KC];
#pragma unroll
    for (int k = 0; k < KC; k++) {
        ca[k] = tab[d * KC + k];
        cb[k] = tab[DK + d * KC + k];
        cc[k] = tab[2 * DK + d * KC + k];
    }
    const int n0 = blockIdx.x * NT;
    float local = 0.f;
#pragma unroll 1
    for (int nn = 0; nn < NT; nn++) {
        int n = n0 + nn;
        const u16* orow = in_agg + ((size_t)n * H + h) * ONC;
        float mean = bf1(orow[tid]);
        float raw  = bf1(orow[HIDC + tid]);
        float sp = fmaxf(raw, 0.f) + __logf(1.f + __expf(-fabsf(raw)));
        float stdv = sp + 1e-10f;
        float ep = eps[(size_t)n * D + d];
        float Z = fmaf(stdv, ep, mean);
        float hv = (Z > 0.f) ? Z : (__expf(Z) - 1.f);   // elu
        if (BF16OUT) ((u16*)hout_)[(size_t)n * D + d] = (u16)f2bf(hv);
        else         ((float*)hout_)[(size_t)n * D + d] = hv;
        float logq = fmaf(-0.5f, ep * ep, -__logf(stdv)) - 0.5f * LOG2PI_F;
        float comp[KC]; float mx = -3.4e38f;
#pragma unroll
        for (int k = 0; k < KC; k++) {
            float cval = fmaf(fmaf(ca[k], Z, cb[k]), Z, cc[k]);
            comp[k] = cval;
            mx = fmaxf(mx, cval);
        }
        float se = 0.f;
#pragma unroll
        for (int k = 0; k < KC; k++) se += __expf(comp[k] - mx);
        local += logq - (mx + __logf(se));
    }
#pragma unroll
    for (int o = 32; o > 0; o >>= 1) local += __shfl_down(local, o, 64);
    __shared__ float red[4];
    int lane = tid & 63, wid = tid >> 6;
    if (lane == 0) red[wid] = local;
    __syncthreads();
    if (tid == 0) {
        atomicAdd(ixz_acc, (red[0] + red[1] + red[2] + red[3]) * (1.0f / NN));
    }
}

// ---------------- final FC ----------------
__global__ void fc_kernel(const float* __restrict__ h, const float* __restrict__ W,
                          const float* __restrict__ b, float* __restrict__ out) {
    int idx = blockIdx.x * blockDim.x + threadIdx.x;
    if (idx >= NN * OUTC) return;
    int n = idx / OUTC, o = idx - n * OUTC;
    const float* hr = h + (size_t)n * D2C;
    float acc = b[o];
#pragma unroll 8
    for (int c = 0; c < D2C; c++) acc += hr[c] * W[c * OUTC + o];
    out[idx] = acc;
}

// ---------------- launch ----------------
extern "C" void kernel_launch(void* const* d_in, const int* in_sizes, int n_in,
                              void* d_out, int out_size, void* d_ws, size_t ws_size,
                              hipStream_t stream) {
    (void)in_sizes; (void)n_in; (void)out_size; (void)ws_size;
    const float* x       = (const float*)d_in[0];
    const int*   ei      = (const int*)d_in[1];
    const float* W1      = (const float*)d_in[2];
    const float* att1    = (const float*)d_in[3];
    const float* pi1     = (const float*)d_in[4];
    const float* mu1     = (const float*)d_in[5];
    const float* logsig1 = (const float*)d_in[6];
    const float* eps1    = (const float*)d_in[7];
    const float* g1      = (const float*)d_in[8];
    const float* W2      = (const float*)d_in[9];
    const float* att2    = (const float*)d_in[10];
    const float* pi2     = (const float*)d_in[11];
    const float* mu2     = (const float*)d_in[12];
    const float* logsig2 = (const float*)d_in[13];
    const float* eps2    = (const float*)d_in[14];
    const float* g2      = (const float*)d_in[15];
    const float* Wfc     = (const float*)d_in[16];
    const float* bfc     = (const float*)d_in[17];
    float* out = (float*)d_out;

    // workspace layout
    char* ws = (char*)d_ws;
    const size_t szAB = (size_t)NN * 2048 * sizeof(float);
    char* regA = ws;
    char* regB = ws + szAB;
    size_t cur = 2 * szAB;
    auto alloc = [&](size_t bytes) -> char* {
        char* p = ws + cur;
        cur += (bytes + 255) & ~(size_t)255;
        return p;
    };
    float* alphaB   = (float*)alloc((size_t)EC * H1C * sizeof(float));  // CSR-order alpha
    float* s_i1     = (float*)alloc((size_t)NN * H1C * sizeof(float));
    float* s_j1     = (float*)alloc((size_t)NN * H1C * sizeof(float));
    float* s_i2     = (float*)alloc((size_t)NN * H2C * sizeof(float));
    float* s_j2     = (float*)alloc((size_t)NN * H2C * sizeof(float));
    int*   deg_i    = (int*)alloc(NN * sizeof(int));
    int*   offs     = (int*)alloc((NN + 1) * sizeof(int));
    int*   cursor   = (int*)alloc(NN * sizeof(int));
    int*   csr_src  = (int*)alloc(EC * sizeof(int));
    int*   csr_eid  = (int*)alloc(EC * sizeof(int));
    u16*   xb1     = (u16*)alloc((size_t)NN * INC * sizeof(u16));      // x in bf16
    u16*   w1t     = (u16*)alloc((size_t)2048 * 512 * sizeof(u16));    // W1^T bf16 [N][K]
    u16*   w2t     = (u16*)alloc((size_t)512 * 1024 * sizeof(u16));    // W2^T bf16 [N][K]
    float* tab1    = (float*)alloc((size_t)3 * D1C * KC * sizeof(float));
    float* tab2    = (float*)alloc((size_t)3 * D2C * KC * sizeof(float));

    // region assignments (stream-ordered reuse):
    u16*   xh1b = (u16*)regA;       // N x 2048 bf16 (GEMM1 out)
    u16*   out1 = (u16*)regB;       // N x 2048 bf16 (gather1 out)
    u16*   h1b  = (u16*)regA;       // N x 1024 bf16 (xh1b dead after gather1)
    u16*   xh2b = (u16*)regB;       // N x 512 bf16 (out1 dead after zixz1)
    u16*   out2 = (u16*)regA;       // N x 512 bf16 (h1b dead after GEMM2)
    float* h2   = (float*)(regB + (size_t)NN * 512 * sizeof(u16)); // N x 256 fp32 (after xh2b)
    float* kl_acc  = out + (size_t)NN * OUTC;      // d_out[100000]
    float* ixz_acc = kl_acc + 1;                   // d_out[100001]

    const int ZB = 256;
    // --- init all accumulators in one dispatch ---
    init_zero<<<(NN * H1C + ZB - 1) / ZB, ZB, 0, stream>>>(
        (unsigned*)deg_i, (unsigned*)cursor, (unsigned*)s_i1, (unsigned*)s_j1,
        (unsigned*)s_i2, (unsigned*)s_j2, (unsigned*)kl_acc);

    // --- graph preprocessing (shared by both layers) ---
    count_deg<<<(EC + ZB - 1) / ZB, ZB, 0, stream>>>(ei, deg_i);
    scan_kernel<<<1, 1024, 0, stream>>>(deg_i, offs);
    csr_fill<<<(EC + ZB - 1) / ZB, ZB, 0, stream>>>(ei, cursor, offs, csr_src, csr_eid);

    // --- bf16 weight/input preparation + mixture tables ---
    cast_bf16<<<(NN * INC / 4 + ZB - 1) / ZB, ZB, 0, stream>>>(x, xb1, NN * INC / 4);
    transpose_cast_both<<<dim3(64, 48), dim3(32, 8), 0, stream>>>(W1, w1t, W2, w2t);
    mix_tables<<<((D1C + D2C) * KC + ZB - 1) / ZB, ZB, 0, stream>>>(
        pi1, mu1, logsig1, tab1, pi2, mu2, logsig2, tab2);

    const int MG = (NN + 127) / 128;   // 79

    // ================= layer 1 (H=4) =================
    mfma_gemm3<H1C, true><<<dim3(2048 / 128, MG), 256, 0, stream>>>(
        xb1, w1t, xh1b, att1, s_i1, s_j1, NN, 2048, 512);
    attn_fused<H1C, 8><<<(NN * H1C + 31) / 32, 256, 0, stream>>>(offs, csr_src, csr_eid,
                                                                 s_i1, s_j1, g1, alphaB, kl_acc,
                                                                 1.0f / (float)(EC * H1C));
    gather_reg2<H1C, 8><<<8 * (NN / 8), 256, 0, stream>>>(xh1b, alphaB, offs, csr_src, out1);
    zixz4_kernel<10, true><<<NN / 10, 256, 0, stream>>>(out1, eps1, tab1, (void*)h1b, ixz_acc);

    // ================= layer 2 (H=1) =================
    mfma_gemm3<H2C, true><<<dim3(512 / 128, MG), 256, 0, stream>>>(
        h1b, w2t, xh2b, att2, s_i2, s_j2, NN, 512, 1024);
    attn_fused<H2C, 8><<<(NN * H2C + 31) / 32, 256, 0, stream>>>(offs, csr_src, csr_eid,
                                                                 s_i2, s_j2, g2, alphaB, kl_acc,
                                                                 1.0f / (float)(EC * H2C));
    gather_reg2<H2C, 2><<<2 * (NN / 8), 256, 0, stream>>>(xh2b, alphaB, offs, csr_src, out2);
    zixz3_kernel<H2C, 10, false><<<dim3(NN / 10, H2C), 256, 0, stream>>>(out2, eps2, tab2, (void*)h2, ixz_acc);

    // ================= FC head =================
    fc_kernel<<<(NN * OUTC + ZB - 1) / ZB, ZB, 0, stream>>>(h2, Wfc, bfc, out);
}